// Round 3
// baseline (3690.031 us; speedup 1.0000x reference)
//
#include <hip/hip_runtime.h>
#include <hip/hip_bf16.h>

#define THREADS 576

typedef __hip_bfloat16 bf16;
typedef __attribute__((ext_vector_type(4))) float f32x4;
typedef __attribute__((ext_vector_type(8))) short bf16x8;

#define MFMA __builtin_amdgcn_mfma_f32_16x16x32_bf16

// ---- LDS layout (bf16 element offsets), blocks of 512 = one 16x32 fragment tile
#define O_A1  0       // [buf0|buf1] x 4mt : [x(2)|h1(16)|pad]
#define O_AY  4096    // 4mt x 2kc : [y(36)|pad]
#define O_AT1 8192    // 4mt x 2kc : t1(64)
#define O_A2  12288   // 4mt x 6kc : [l2(72)|pad(24) | h2(72)@k96|pad]
#define O_AH3 24576   // 4mt x 1kc : h3(32)
#define LDS_ELEMS 26624
#define LDS_BYTES (LDS_ELEMS * 2)   // 53248 -> 3 WGs/CU

// self-consistent K mapping within a 16x32 fragment tile (verified round 1)
__device__ __forceinline__ int kmap(int l, int j) {
    return (((l >> 4) & 3) << 2) + (j & 3) + ((j >> 2) << 4);
}
__device__ __forceinline__ int frag_off(int m, int k) { // k in [0,32)
    int l = (m & 15) | (((k >> 2) & 3) << 4);
    int j = (k & 3) | (((k >> 4) & 1) << 2);
    return (l << 3) + j;
}
__device__ __forceinline__ void st_frag(bf16* sbase, int KC, int m, int k, float v) {
    sbase[(((m >> 4) * KC + (k >> 5)) << 9) + frag_off(m, k & 31)] = __float2bfloat16(v);
}

__device__ __forceinline__ float rcp_(float x) { return __builtin_amdgcn_rcpf(x); }
__device__ __forceinline__ float sigm(float x) { return rcp_(1.0f + __expf(-x)); }
__device__ __forceinline__ float tanh_(float x) { return 1.0f - 2.0f * rcp_(1.0f + __expf(2.0f * x)); }

__device__ __forceinline__ float pick4(float a, float b, float c, float d, int j) {
    float ab = (j & 1) ? b : a;
    float cd = (j & 1) ? d : c;
    return (j & 2) ? cd : ab;
}

// quad-lane xor exchange via DPP (VALU, no DS op). xor1=0xB1, xor2=0x4E, xor3=0x1B
template <int CTRL>
__device__ __forceinline__ float qperm(float v) {
    return __int_as_float(__builtin_amdgcn_mov_dpp(__float_as_int(v), CTRL, 0xF, 0xF, true));
}

__device__ __forceinline__ ushort bfu(float f) {
    union { bf16 b; ushort u; } v; v.b = __float2bfloat16(f); return v.u;
}

// fused gate-EW for interleaved-gate tiles: col n = h*4+g ; lane (g=lane&3) does row base+g
template <typename WR>
__device__ __forceinline__ void lstm_tile_ew(f32x4 acc, float bias, float& cst, int lane, WR wr) {
    int g = lane & 3;
    float a0 = acc[0] + bias, a1 = acc[1] + bias, a2 = acc[2] + bias, a3 = acc[3] + bias;
    float own = pick4(a0, a1, a2, a3, g);
    float p1 = pick4(a0, a1, a2, a3, g ^ 1);
    float p2 = pick4(a0, a1, a2, a3, g ^ 2);
    float p3 = pick4(a0, a1, a2, a3, g ^ 3);
    float q1 = qperm<0xB1>(p1);
    float q2 = qperm<0x4E>(p2);
    float q3 = qperm<0x1B>(p3);
    float iv = pick4(own, q1, q2, q3, g);
    float fv = pick4(own, q1, q2, q3, g ^ 1);
    float gv = pick4(own, q1, q2, q3, g ^ 2);
    float ov = pick4(own, q1, q2, q3, g ^ 3);
    float c = sigm(fv) * cst + sigm(iv) * tanh_(gv);
    cst = c;
    wr(sigm(ov) * tanh_(c));
}

template <typename F>
__device__ __forceinline__ bf16x8 mk_frag(int lane, F val) { // val(k), k in [0,32)
    union { bf16x8 v; bf16 h[8]; } u;
#pragma unroll
    for (int j = 0; j < 8; ++j) u.h[j] = __float2bfloat16(val(kmap(lane, j)));
    return u.v;
}

__global__ void __launch_bounds__(THREADS)
lstm_fused(const float* __restrict__ x, const float* __restrict__ y,
           const float* __restrict__ Wih1, const float* __restrict__ Whh1,
           const float* __restrict__ bih1, const float* __restrict__ bhh1,
           const float* __restrict__ Wih2, const float* __restrict__ Whh2,
           const float* __restrict__ bih2, const float* __restrict__ bhh2,
           const float* __restrict__ Wih3, const float* __restrict__ Whh3,
           const float* __restrict__ bih3, const float* __restrict__ bhh3,
           const float* __restrict__ W1, const float* __restrict__ b1,
           const float* __restrict__ W2, const float* __restrict__ b2,
           const float* __restrict__ W3, const float* __restrict__ b3,
           const float* __restrict__ W4, const float* __restrict__ b4,
           float* __restrict__ out) {
    extern __shared__ char smem[];
    bf16* sb = (bf16*)smem;
    const int tid = threadIdx.x;
    const int wave = tid >> 6, lane = tid & 63, ln15 = lane & 15;
    const int b0 = blockIdx.x * 64;

    // ---- per-wave register-resident B fragments + biases ----
    bf16x8 bL1 = {};  float biasL1 = 0.f;
    bf16x8 bF1[2] = {}; float biasF1 = 0.f;
    bf16x8 bF2[2] = {}; float biasF2 = 0.f;
    bf16x8 bL2[2][6]; float biasL2[2];
    bf16x8 bL3[5] = {}; float biasL3 = 0.f;
    bf16x8 bF3 = {};  float biasF3 = 0.f, w40 = 0.f, w41 = 0.f, b40 = 0.f, b41 = 0.f;

    if (wave < 4) { // LSTM1 gates interleaved: nt=wave, H=16
        int n = (wave << 4) + ln15;
        int r = (n & 3) * 16 + (n >> 2);
        biasL1 = bih1[r] + bhh1[r];
        bL1 = mk_frag(lane, [&](int k) {
            return k < 2 ? Wih1[r * 2 + k] : (k < 18 ? Whh1[r * 16 + (k - 2)] : 0.0f); });
    }
    if (wave >= 4 && wave < 8) { // FC1: nt=wave-4
        int n = ((wave - 4) << 4) + ln15;
        biasF1 = b1[n];
#pragma unroll
        for (int kc = 0; kc < 2; ++kc)
            bF1[kc] = mk_frag(lane, [&](int kl) {
                int k = kc * 32 + kl; return k < 36 ? W1[n * 36 + k] : 0.0f; });
        // FC3 + FC4 (P5 on waves 4-7)
        int n3 = ln15;
        biasF3 = b3[n3]; w40 = W4[n3]; w41 = W4[16 + n3];
        b40 = b4[0]; b41 = b4[1];
        bF3 = mk_frag(lane, [&](int k) { return W3[n3 * 32 + k]; });
    }
    if (wave < 5) { // FC2: nt=wave, 72 cols
        int n = (wave << 4) + ln15;
        biasF2 = (n < 72) ? b2[n] : 0.0f;
#pragma unroll
        for (int kc = 0; kc < 2; ++kc)
            bF2[kc] = mk_frag(lane, [&](int kl) {
                int k = kc * 32 + kl; return (n < 72) ? W2[n * 64 + k] : 0.0f; });
    }
#pragma unroll
    for (int ntl = 0; ntl < 2; ++ntl) { // LSTM2 interleaved: nt = wave + ntl*9, H=72
        int n = ((wave + ntl * 9) << 4) + ln15;
        int r = (n & 3) * 72 + (n >> 2);
        biasL2[ntl] = bih2[r] + bhh2[r];
#pragma unroll
        for (int b = 0; b < 6; ++b)
            bL2[ntl][b] = mk_frag(lane, [&](int kl) {
                if (b < 3) { int k = b * 32 + kl; return k < 72 ? Wih2[r * 72 + k] : 0.0f; }
                int k = (b - 3) * 32 + kl; return k < 72 ? Whh2[r * 72 + k] : 0.0f; });
    }
    if (wave < 8) { // LSTM3 interleaved: nt=wave, H=32
        int n = (wave << 4) + ln15;
        int r = (n & 3) * 32 + (n >> 2);
        biasL3 = bih3[r] + bhh3[r];
        // b0 <- A1 tile [x(2)|h1(16)|pad14] ; b1..3 <- A2 h2 slots ; b4 <- AH3 h3
        bL3[0] = mk_frag(lane, [&](int k) {
            return (k >= 2 && k < 18) ? Wih3[r * 88 + (k - 2)] : 0.0f; });
#pragma unroll
        for (int j = 0; j < 3; ++j)
            bL3[1 + j] = mk_frag(lane, [&](int kl) {
                int h2 = j * 32 + kl; return h2 < 72 ? Wih3[r * 88 + 16 + h2] : 0.0f; });
        bL3[4] = mk_frag(lane, [&](int k) { return Whh3[r * 32 + k]; });
    }

    // ---- zero LDS ----
    {
        int4* z = (int4*)sb;
        int4 zv = {0, 0, 0, 0};
        for (int i = tid; i < LDS_BYTES / 16; i += THREADS) z[i] = zv;
    }
    __syncthreads();
    // ---- stage x(0), y(0) ----
    if (tid < 128) {
        int m = tid >> 1, k = tid & 1;
        st_frag(sb + O_A1, 1, m, k, x[(size_t)(b0 + m) * 50 + k]);
    }
    for (int it = tid; it < 64 * 36; it += THREADS) {
        int m = it / 36, k = it - m * 36;
        st_frag(sb + O_AY, 2, m, k, y[(size_t)(b0 + m) * 900 + k]);
    }
    float c1[4] = {0.f, 0.f, 0.f, 0.f};
    float c2[2][4] = {{0.f, 0.f, 0.f, 0.f}, {0.f, 0.f, 0.f, 0.f}};
    float c3[4] = {0.f, 0.f, 0.f, 0.f};
    ushort4 ypk[9]; uint xpk = 0;
    __syncthreads();

    for (int t = 0; t < 25; ++t) {
        const int rs = t & 1, ws = rs ^ 1;

        // ---- P1: LSTM1 (w0-3) | FC1 (w4-7) | y/x(t+1) load (w8) ----
        if (wave < 4) {
            const bf16* A = sb + O_A1 + ((rs * 4) << 9);
#pragma unroll
            for (int mt = 0; mt < 4; ++mt) {
                bf16x8 a = *(const bf16x8*)(A + (mt << 9) + (lane << 3));
                f32x4 acc = {0.f, 0.f, 0.f, 0.f};
                acc = MFMA(a, bL1, acc, 0, 0, 0);
                lstm_tile_ew(acc, biasL1, c1[mt], lane, [&](float hv) {
                    int m = (mt << 4) + ((lane >> 4) << 2) + (lane & 3);
                    int h = (wave << 2) + ((lane >> 2) & 3);
                    st_frag(sb + O_A1 + ((ws * 4) << 9), 1, m, 2 + h, hv);
                });
            }
        } else if (wave < 8) {
            const int nt = wave - 4;
#pragma unroll
            for (int mt = 0; mt < 4; ++mt) {
                f32x4 acc = {0.f, 0.f, 0.f, 0.f};
#pragma unroll
                for (int kc = 0; kc < 2; ++kc) {
                    bf16x8 a = *(const bf16x8*)(sb + O_AY + ((mt * 2 + kc) << 9) + (lane << 3));
                    acc = MFMA(a, bF1[kc], acc, 0, 0, 0);
                }
                int n = (nt << 4) + ln15;
                int mrow = (mt << 4) + ((lane >> 4) << 2);
#pragma unroll
                for (int r = 0; r < 4; ++r)
                    st_frag(sb + O_AT1, 2, mrow + r, n, fmaxf(acc[r] + biasF1, 0.0f));
            }
        } else if (t < 24) {
            const float* yp = y + (size_t)(b0 + lane) * 900 + (t + 1) * 36;
            float4 yv[9];
#pragma unroll
            for (int c = 0; c < 9; ++c) yv[c] = *(const float4*)(yp + c * 4);
            float2 xv = *(const float2*)(x + (size_t)(b0 + lane) * 50 + (t + 1) * 2);
#pragma unroll
            for (int c = 0; c < 9; ++c) {
                ypk[c].x = bfu(yv[c].x); ypk[c].y = bfu(yv[c].y);
                ypk[c].z = bfu(yv[c].z); ypk[c].w = bfu(yv[c].w);
            }
            union { uint u; ushort s[2]; } xu;
            xu.s[0] = bfu(xv.x); xu.s[1] = bfu(xv.y);
            xpk = xu.u;
        }
        __syncthreads();

        // ---- P2: FC2 (w0-4) | staged ds_writes (w8) ----
        if (wave < 5) {
#pragma unroll
            for (int mt = 0; mt < 4; ++mt) {
                f32x4 acc = {0.f, 0.f, 0.f, 0.f};
#pragma unroll
                for (int kc = 0; kc < 2; ++kc) {
                    bf16x8 a = *(const bf16x8*)(sb + O_AT1 + ((mt * 2 + kc) << 9) + (lane << 3));
                    acc = MFMA(a, bF2[kc], acc, 0, 0, 0);
                }
                int n = (wave << 4) + ln15;
                if (n < 72) {
                    int mrow = (mt << 4) + ((lane >> 4) << 2);
#pragma unroll
                    for (int r = 0; r < 4; ++r)
                        st_frag(sb + O_A2, 6, mrow + r, n, acc[r] + biasF2);
                }
            }
        } else if (wave == 8 && t < 24) {
            const int m = lane, mt = m >> 4;
#pragma unroll
            for (int c = 0; c < 9; ++c) {
                int k0 = 4 * c;
                int l2v = (m & 15) | (((k0 >> 2) & 3) << 4);
                int j0 = ((k0 >> 4) & 1) << 2;
                ushort* dst = (ushort*)(sb + O_AY) + (((mt * 2 + (k0 >> 5)) << 9) + (l2v << 3) + j0);
                *(ushort4*)dst = ypk[c];
            }
            *(uint*)((ushort*)(sb + O_A1) + (((ws * 4 + mt) << 9) + ((m & 15) << 3))) = xpk;
        }
        __syncthreads();

        // ---- P3a: LSTM2 MFMA (all 9 waves) -> regs ----
        f32x4 acc2[2][4];
#pragma unroll
        for (int ntl = 0; ntl < 2; ++ntl) {
#pragma unroll
            for (int mt = 0; mt < 4; ++mt) {
                f32x4 acc = {0.f, 0.f, 0.f, 0.f};
#pragma unroll
                for (int b = 0; b < 6; ++b) {
                    bf16x8 a = *(const bf16x8*)(sb + O_A2 + ((mt * 6 + b) << 9) + (lane << 3));
                    acc = MFMA(a, bL2[ntl][b], acc, 0, 0, 0);
                }
                acc2[ntl][mt] = acc;
            }
        }
        __syncthreads();

        // ---- P3b: LSTM2 EW -> h2 back into A2 (k=96+h) ----
#pragma unroll
        for (int ntl = 0; ntl < 2; ++ntl) {
            const int nt = wave + ntl * 9;
#pragma unroll
            for (int mt = 0; mt < 4; ++mt) {
                lstm_tile_ew(acc2[ntl][mt], biasL2[ntl], c2[ntl][mt], lane, [&](float hv) {
                    int m = (mt << 4) + ((lane >> 4) << 2) + (lane & 3);
                    int h = (nt << 2) + ((lane >> 2) & 3);
                    st_frag(sb + O_A2, 6, m, 96 + h, hv);
                });
            }
        }
        __syncthreads();

        // ---- P4a: LSTM3 MFMA (w0-7): A from A1[ws] + A2-h2 + AH3 ----
        f32x4 acc3[4];
        if (wave < 8) {
#pragma unroll
            for (int mt = 0; mt < 4; ++mt) {
                f32x4 acc = {0.f, 0.f, 0.f, 0.f};
                bf16x8 a0 = *(const bf16x8*)(sb + O_A1 + ((ws * 4 + mt) << 9) + (lane << 3));
                acc = MFMA(a0, bL3[0], acc, 0, 0, 0);
#pragma unroll
                for (int j = 0; j < 3; ++j) {
                    bf16x8 a = *(const bf16x8*)(sb + O_A2 + ((mt * 6 + 3 + j) << 9) + (lane << 3));
                    acc = MFMA(a, bL3[1 + j], acc, 0, 0, 0);
                }
                bf16x8 a4 = *(const bf16x8*)(sb + O_AH3 + (mt << 9) + (lane << 3));
                acc = MFMA(a4, bL3[4], acc, 0, 0, 0);
                acc3[mt] = acc;
            }
        }
        __syncthreads();

        // ---- P4b: LSTM3 EW -> h3 into AH3 ----
        if (wave < 8) {
#pragma unroll
            for (int mt = 0; mt < 4; ++mt) {
                lstm_tile_ew(acc3[mt], biasL3, c3[mt], lane, [&](float hv) {
                    int m = (mt << 4) + ((lane >> 4) << 2) + (lane & 3);
                    int h = (wave << 2) + ((lane >> 2) & 3);
                    st_frag(sb + O_AH3, 1, m, h, hv);
                });
            }
        }
        __syncthreads();

        // ---- P5: FC3 + FC4 (w4-7, mt=wave-4) -> out ; no trailing barrier ----
        if (wave >= 4 && wave < 8) {
            const int mt = wave - 4;
            bf16x8 a = *(const bf16x8*)(sb + O_AH3 + (mt << 9) + (lane << 3));
            f32x4 acc = {0.f, 0.f, 0.f, 0.f};
            acc = MFMA(a, bF3, acc, 0, 0, 0);
            f32x4 s0, s1;
#pragma unroll
            for (int r = 0; r < 4; ++r) {
                float u = fmaxf(acc[r] + biasF3, 0.0f);
                s0[r] = u * w40; s1[r] = u * w41;
            }
#pragma unroll
            for (int msk = 1; msk < 16; msk <<= 1) {
#pragma unroll
                for (int r = 0; r < 4; ++r) {
                    s0[r] += __shfl_xor(s0[r], msk, 64);
                    s1[r] += __shfl_xor(s1[r], msk, 64);
                }
            }
            if (ln15 == 0) {
                int mrow = (mt << 4) + ((lane >> 4) << 2);
#pragma unroll
                for (int r = 0; r < 4; ++r) {
                    float2 o; o.x = s0[r] + b40; o.y = s1[r] + b41;
                    *(float2*)(out + (size_t)(b0 + mrow + r) * 50 + t * 2) = o;
                }
            }
        }
    }
}

extern "C" void kernel_launch(void* const* d_in, const int* in_sizes, int n_in,
                              void* d_out, int out_size, void* d_ws, size_t ws_size,
                              hipStream_t stream) {
    (void)in_sizes; (void)n_in; (void)d_ws; (void)ws_size; (void)out_size;
    hipFuncSetAttribute((const void*)lstm_fused,
                        hipFuncAttributeMaxDynamicSharedMemorySize, LDS_BYTES);
    lstm_fused<<<dim3(2048), dim3(THREADS), LDS_BYTES, stream>>>(
        (const float*)d_in[0], (const float*)d_in[1],
        (const float*)d_in[2], (const float*)d_in[3],
        (const float*)d_in[4], (const float*)d_in[5],
        (const float*)d_in[6], (const float*)d_in[7],
        (const float*)d_in[8], (const float*)d_in[9],
        (const float*)d_in[10], (const float*)d_in[11],
        (const float*)d_in[12], (const float*)d_in[13],
        (const float*)d_in[14], (const float*)d_in[15],
        (const float*)d_in[16], (const float*)d_in[17],
        (const float*)d_in[18], (const float*)d_in[19],
        (const float*)d_in[20], (const float*)d_in[21],
        (float*)d_out);
}

// Round 4
// 1777.304 us; speedup vs baseline: 2.0762x; 2.0762x over previous
//
#include <hip/hip_runtime.h>
#include <hip/hip_bf16.h>

#define THREADS 576

typedef __hip_bfloat16 bf16;
typedef __attribute__((ext_vector_type(4))) float f32x4;
typedef __attribute__((ext_vector_type(8))) short bf16x8;

#define MFMA __builtin_amdgcn_mfma_f32_16x16x32_bf16

// ---- LDS layout (bf16 element offsets), blocks of 512 = one 16x32 fragment tile
#define O_A1  0       // 2 slots x 4mt : [x(2)|h1(16)|pad14]
#define O_AY  4096    // 4mt x 2kc : [y(36)|pad]
#define O_AT1 8192    // 4mt x 2kc : t1(64)
#define O_A2  12288   // 4mt x 9kc : [l2(72)|pad24 | h2 slot0 (3kc) | h2 slot1 (3kc)]
#define O_AH3 30720   // 2 slots x 4mt : h3(32)
#define LDS_ELEMS 34816
#define LDS_BYTES (LDS_ELEMS * 2)   // 69632

// self-consistent K mapping within a 16x32 fragment tile (verified round 1)
__device__ __forceinline__ int kmap(int l, int j) {
    return (((l >> 4) & 3) << 2) + (j & 3) + ((j >> 2) << 4);
}
__device__ __forceinline__ int frag_off(int m, int k) { // k in [0,32)
    int l = (m & 15) | (((k >> 2) & 3) << 4);
    int j = (k & 3) | (((k >> 4) & 1) << 2);
    return (l << 3) + j;
}
__device__ __forceinline__ void st_frag(bf16* sbase, int KC, int m, int k, float v) {
    sbase[(((m >> 4) * KC + (k >> 5)) << 9) + frag_off(m, k & 31)] = __float2bfloat16(v);
}

__device__ __forceinline__ float rcp_(float x) { return __builtin_amdgcn_rcpf(x); }
__device__ __forceinline__ float sigm(float x) { return rcp_(1.0f + __expf(-x)); }
__device__ __forceinline__ float tanh_(float x) { return 1.0f - 2.0f * rcp_(1.0f + __expf(2.0f * x)); }

__device__ __forceinline__ float pick4(float a, float b, float c, float d, int j) {
    float ab = (j & 1) ? b : a;
    float cd = (j & 1) ? d : c;
    return (j & 2) ? cd : ab;
}

// DPP lane permute (VALU, no DS op). quad xor1=0xB1, xor2=0x4E, xor3=0x1B; row_ror4=0x124, ror8=0x128
template <int CTRL>
__device__ __forceinline__ float qperm(float v) {
    return __int_as_float(__builtin_amdgcn_mov_dpp(__float_as_int(v), CTRL, 0xF, 0xF, true));
}

__device__ __forceinline__ ushort bfu(float f) {
    union { bf16 b; ushort u; } v; v.b = __float2bfloat16(f); return v.u;
}

// fused gate-EW for interleaved-gate tiles: col n = h*4+g ; lane (g=lane&3) does row base+g
template <typename WR>
__device__ __forceinline__ void lstm_tile_ew(f32x4 acc, float bias, float& cst, int lane, WR wr) {
    int g = lane & 3;
    float a0 = acc[0] + bias, a1 = acc[1] + bias, a2 = acc[2] + bias, a3 = acc[3] + bias;
    float own = pick4(a0, a1, a2, a3, g);
    float p1 = pick4(a0, a1, a2, a3, g ^ 1);
    float p2 = pick4(a0, a1, a2, a3, g ^ 2);
    float p3 = pick4(a0, a1, a2, a3, g ^ 3);
    float q1 = qperm<0xB1>(p1);
    float q2 = qperm<0x4E>(p2);
    float q3 = qperm<0x1B>(p3);
    float iv = pick4(own, q1, q2, q3, g);
    float fv = pick4(own, q1, q2, q3, g ^ 1);
    float gv = pick4(own, q1, q2, q3, g ^ 2);
    float ov = pick4(own, q1, q2, q3, g ^ 3);
    float c = sigm(fv) * cst + sigm(iv) * tanh_(gv);
    cst = c;
    wr(sigm(ov) * tanh_(c));
}

template <typename F>
__device__ __forceinline__ bf16x8 mk_frag(int lane, F val) { // val(k), k in [0,32)
    union { bf16x8 v; bf16 h[8]; } u;
#pragma unroll
    for (int j = 0; j < 8; ++j) u.h[j] = __float2bfloat16(val(kmap(lane, j)));
    return u.v;
}

__global__ void __launch_bounds__(THREADS)
lstm_fused(const float* __restrict__ x, const float* __restrict__ y,
           const float* __restrict__ Wih1, const float* __restrict__ Whh1,
           const float* __restrict__ bih1, const float* __restrict__ bhh1,
           const float* __restrict__ Wih2, const float* __restrict__ Whh2,
           const float* __restrict__ bih2, const float* __restrict__ bhh2,
           const float* __restrict__ Wih3, const float* __restrict__ Whh3,
           const float* __restrict__ bih3, const float* __restrict__ bhh3,
           const float* __restrict__ W1, const float* __restrict__ b1,
           const float* __restrict__ W2, const float* __restrict__ b2,
           const float* __restrict__ W3, const float* __restrict__ b3,
           const float* __restrict__ W4, const float* __restrict__ b4,
           float* __restrict__ out) {
    extern __shared__ char smem[];
    bf16* sb = (bf16*)smem;
    const int tid = threadIdx.x;
    const int wave = tid >> 6, lane = tid & 63, ln15 = lane & 15;
    const int b0 = blockIdx.x * 64;

    // ---- per-wave register-resident B fragments + biases ----
    bf16x8 bL1 = {};  float biasL1 = 0.f;
    bf16x8 bF1[2] = {}; float biasF1 = 0.f;
    bf16x8 bF2[2] = {}; float biasF2 = 0.f;
    bf16x8 bL2[2][6]; float biasL2[2];
    bf16x8 bL3[5] = {}; float biasL3 = 0.f;
    bf16x8 bF3 = {};  float biasF3 = 0.f, w40 = 0.f, w41 = 0.f, b40 = 0.f, b41 = 0.f;

    if (wave < 4) { // LSTM1 gates interleaved: nt=wave, H=16
        int n = (wave << 4) + ln15;
        int r = (n & 3) * 16 + (n >> 2);
        biasL1 = bih1[r] + bhh1[r];
        bL1 = mk_frag(lane, [&](int k) {
            return k < 2 ? Wih1[r * 2 + k] : (k < 18 ? Whh1[r * 16 + (k - 2)] : 0.0f); });
    }
    if (wave >= 4 && wave < 8) { // FC1: nt=wave-4
        int n = ((wave - 4) << 4) + ln15;
        biasF1 = b1[n];
#pragma unroll
        for (int kc = 0; kc < 2; ++kc)
            bF1[kc] = mk_frag(lane, [&](int kl) {
                int k = kc * 32 + kl; return k < 36 ? W1[n * 36 + k] : 0.0f; });
    }
    if (wave < 5) { // FC2: nt=wave, 72 cols
        int n = (wave << 4) + ln15;
        biasF2 = (n < 72) ? b2[n] : 0.0f;
#pragma unroll
        for (int kc = 0; kc < 2; ++kc)
            bF2[kc] = mk_frag(lane, [&](int kl) {
                int k = kc * 32 + kl; return (n < 72) ? W2[n * 64 + k] : 0.0f; });
    }
#pragma unroll
    for (int ntl = 0; ntl < 2; ++ntl) { // LSTM2 interleaved: nt = wave + ntl*9, H=72
        int n = ((wave + ntl * 9) << 4) + ln15;
        int r = (n & 3) * 72 + (n >> 2);
        biasL2[ntl] = bih2[r] + bhh2[r];
#pragma unroll
        for (int b = 0; b < 6; ++b)
            bL2[ntl][b] = mk_frag(lane, [&](int kl) {
                if (b < 3) { int k = b * 32 + kl; return k < 72 ? Wih2[r * 72 + k] : 0.0f; }
                int k = (b - 3) * 32 + kl; return k < 72 ? Whh2[r * 72 + k] : 0.0f; });
    }
    if (wave < 8) { // LSTM3 interleaved: nt=wave, H=32
        int n = (wave << 4) + ln15;
        int r = (n & 3) * 32 + (n >> 2);
        biasL3 = bih3[r] + bhh3[r];
        // b0 <- A1 tile [x(2)|h1(16)|pad14] ; b1..3 <- A2 h2 slots ; b4 <- AH3 h3
        bL3[0] = mk_frag(lane, [&](int k) {
            return (k >= 2 && k < 18) ? Wih3[r * 88 + (k - 2)] : 0.0f; });
#pragma unroll
        for (int j = 0; j < 3; ++j)
            bL3[1 + j] = mk_frag(lane, [&](int kl) {
                int h2 = j * 32 + kl; return h2 < 72 ? Wih3[r * 88 + 16 + h2] : 0.0f; });
        bL3[4] = mk_frag(lane, [&](int k) { return Whh3[r * 32 + k]; });
    }
    if (wave >= 5) { // FC3 (mt=wave-5, shared nt) + FC4 scalars
        int n3 = ln15;
        biasF3 = b3[n3]; w40 = W4[n3]; w41 = W4[16 + n3];
        b40 = b4[0]; b41 = b4[1];
        bF3 = mk_frag(lane, [&](int k) { return W3[n3 * 32 + k]; });
    }

    // ---- zero LDS ----
    {
        int4* z = (int4*)sb;
        int4 zv = {0, 0, 0, 0};
        for (int i = tid; i < LDS_BYTES / 16; i += THREADS) z[i] = zv;
    }
    __syncthreads();
    // ---- stage x(0), y(0) ----
    if (tid < 128) {
        int m = tid >> 1, k = tid & 1;
        st_frag(sb + O_A1, 1, m, k, x[(size_t)(b0 + m) * 50 + k]);
    }
    for (int it = tid; it < 64 * 36; it += THREADS) {
        int m = it / 36, k = it - m * 36;
        st_frag(sb + O_AY, 2, m, k, y[(size_t)(b0 + m) * 900 + k]);
    }
    float c1[4] = {0.f, 0.f, 0.f, 0.f};
    float c2[2][4] = {{0.f, 0.f, 0.f, 0.f}, {0.f, 0.f, 0.f, 0.f}};
    float c3[4] = {0.f, 0.f, 0.f, 0.f};
    ushort4 ypk[9]; uint xpk = 0;
    __syncthreads();

    for (int t = 0; t < 25; ++t) {
        const int rs = t & 1, ws = rs ^ 1;

        // ---- P1: LSTM1 (w0-3) | FC1 (w4-7) | y/x(t+1) load (w8) ----
        if (wave < 4) {
            const bf16* A = sb + O_A1 + ((rs * 4) << 9);
#pragma unroll
            for (int mt = 0; mt < 4; ++mt) {
                bf16x8 a = *(const bf16x8*)(A + (mt << 9) + (lane << 3));
                f32x4 acc = {0.f, 0.f, 0.f, 0.f};
                acc = MFMA(a, bL1, acc, 0, 0, 0);
                lstm_tile_ew(acc, biasL1, c1[mt], lane, [&](float hv) {
                    int m = (mt << 4) + ((lane >> 4) << 2) + (lane & 3);
                    int h = (wave << 2) + ((lane >> 2) & 3);
                    st_frag(sb + O_A1 + ((ws * 4) << 9), 1, m, 2 + h, hv);
                });
            }
        } else if (wave < 8) {
            const int nt = wave - 4;
#pragma unroll
            for (int mt = 0; mt < 4; ++mt) {
                f32x4 acc = {0.f, 0.f, 0.f, 0.f};
#pragma unroll
                for (int kc = 0; kc < 2; ++kc) {
                    bf16x8 a = *(const bf16x8*)(sb + O_AY + ((mt * 2 + kc) << 9) + (lane << 3));
                    acc = MFMA(a, bF1[kc], acc, 0, 0, 0);
                }
                int n = (nt << 4) + ln15;
                int mrow = (mt << 4) + ((lane >> 4) << 2);
#pragma unroll
                for (int r = 0; r < 4; ++r)
                    st_frag(sb + O_AT1, 2, mrow + r, n, fmaxf(acc[r] + biasF1, 0.0f));
            }
        } else if (t < 24) {
            const float* yp = y + (size_t)(b0 + lane) * 900 + (t + 1) * 36;
            float4 yv[9];
#pragma unroll
            for (int c = 0; c < 9; ++c) yv[c] = *(const float4*)(yp + c * 4);
            float2 xv = *(const float2*)(x + (size_t)(b0 + lane) * 50 + (t + 1) * 2);
#pragma unroll
            for (int c = 0; c < 9; ++c) {
                ypk[c].x = bfu(yv[c].x); ypk[c].y = bfu(yv[c].y);
                ypk[c].z = bfu(yv[c].z); ypk[c].w = bfu(yv[c].w);
            }
            union { uint u; ushort s[2]; } xu;
            xu.s[0] = bfu(xv.x); xu.s[1] = bfu(xv.y);
            xpk = xu.u;
        }
        __syncthreads();

        // ---- P2: FC2 (w0-4) | FC3+FC4(t-1) (w5-8) | staged ds_writes (w8) ----
        if (wave < 5) {
#pragma unroll
            for (int mt = 0; mt < 4; ++mt) {
                f32x4 acc = {0.f, 0.f, 0.f, 0.f};
#pragma unroll
                for (int kc = 0; kc < 2; ++kc) {
                    bf16x8 a = *(const bf16x8*)(sb + O_AT1 + ((mt * 2 + kc) << 9) + (lane << 3));
                    acc = MFMA(a, bF2[kc], acc, 0, 0, 0);
                }
                int n = (wave << 4) + ln15;
                if (n < 72) {
                    int mrow = (mt << 4) + ((lane >> 4) << 2);
#pragma unroll
                    for (int r = 0; r < 4; ++r)
                        st_frag(sb + O_A2, 9, mrow + r, n, acc[r] + biasF2);
                }
            }
        } else {
            if (t > 0) { // FC3+FC4 for step t-1; h3(t-1) is in AH3 slot rs
                const int mt = wave - 5;
                bf16x8 a = *(const bf16x8*)(sb + O_AH3 + ((rs * 4 + mt) << 9) + (lane << 3));
                f32x4 acc = {0.f, 0.f, 0.f, 0.f};
                acc = MFMA(a, bF3, acc, 0, 0, 0);
#pragma unroll
                for (int r = 0; r < 4; ++r) {
                    float u = fmaxf(acc[r] + biasF3, 0.0f);
                    float s0 = u * w40, s1 = u * w41;
                    s0 += qperm<0xB1>(s0);  s1 += qperm<0xB1>(s1);
                    s0 += qperm<0x4E>(s0);  s1 += qperm<0x4E>(s1);
                    s0 += qperm<0x124>(s0); s1 += qperm<0x124>(s1);
                    s0 += qperm<0x128>(s0); s1 += qperm<0x128>(s1);
                    if (ln15 == 0) {
                        int mrow = (mt << 4) + ((lane >> 4) << 2) + r;
                        float2 o; o.x = s0 + b40; o.y = s1 + b41;
                        *(float2*)(out + (size_t)(b0 + mrow) * 50 + (t - 1) * 2) = o;
                    }
                }
            }
            if (wave == 8 && t < 24) {
                const int m = lane, mt = m >> 4;
#pragma unroll
                for (int c = 0; c < 9; ++c) {
                    int k0 = 4 * c;
                    int l2v = (m & 15) | (((k0 >> 2) & 3) << 4);
                    int j0 = ((k0 >> 4) & 1) << 2;
                    ushort* dst = (ushort*)(sb + O_AY) + (((mt * 2 + (k0 >> 5)) << 9) + (l2v << 3) + j0);
                    *(ushort4*)dst = ypk[c];
                }
                *(uint*)((ushort*)(sb + O_A1) + (((ws * 4 + mt) << 9) + ((m & 15) << 3))) = xpk;
            }
        }
        __syncthreads();

        // ---- P3: LSTM2 (all 9 waves), fused EW; A-frags loaded once per mt ----
#pragma unroll
        for (int mt = 0; mt < 4; ++mt) {
            bf16x8 al[6];
#pragma unroll
            for (int j = 0; j < 3; ++j)
                al[j] = *(const bf16x8*)(sb + O_A2 + ((mt * 9 + j) << 9) + (lane << 3));
#pragma unroll
            for (int j = 0; j < 3; ++j)
                al[3 + j] = *(const bf16x8*)(sb + O_A2 + ((mt * 9 + 3 + 3 * rs + j) << 9) + (lane << 3));
#pragma unroll
            for (int ntl = 0; ntl < 2; ++ntl) {
                const int nt = wave + ntl * 9;
                f32x4 acc = {0.f, 0.f, 0.f, 0.f};
#pragma unroll
                for (int b = 0; b < 6; ++b) acc = MFMA(al[b], bL2[ntl][b], acc, 0, 0, 0);
                lstm_tile_ew(acc, biasL2[ntl], c2[ntl][mt], lane, [&](float hv) {
                    int m = (mt << 4) + ((lane >> 4) << 2) + (lane & 3);
                    int h = (nt << 2) + ((lane >> 2) & 3);
                    st_frag(sb + O_A2, 9, m, (3 + 3 * ws) * 32 + h, hv);
                });
            }
        }
        __syncthreads();

        // ---- P4: LSTM3 (w0-7): A from A1[ws](h1 new) + A2 h2[ws](new) + AH3[rs](h3 old) ----
        if (wave < 8) {
#pragma unroll
            for (int mt = 0; mt < 4; ++mt) {
                f32x4 acc = {0.f, 0.f, 0.f, 0.f};
                bf16x8 a0 = *(const bf16x8*)(sb + O_A1 + ((ws * 4 + mt) << 9) + (lane << 3));
                acc = MFMA(a0, bL3[0], acc, 0, 0, 0);
#pragma unroll
                for (int j = 0; j < 3; ++j) {
                    bf16x8 a = *(const bf16x8*)(sb + O_A2 + ((mt * 9 + 3 + 3 * ws + j) << 9) + (lane << 3));
                    acc = MFMA(a, bL3[1 + j], acc, 0, 0, 0);
                }
                bf16x8 a4 = *(const bf16x8*)(sb + O_AH3 + ((rs * 4 + mt) << 9) + (lane << 3));
                acc = MFMA(a4, bL3[4], acc, 0, 0, 0);
                lstm_tile_ew(acc, biasL3, c3[mt], lane, [&](float hv) {
                    int m = (mt << 4) + ((lane >> 4) << 2) + (lane & 3);
                    int h = (wave << 2) + ((lane >> 2) & 3);
                    st_frag(sb + O_AH3 + ((ws * 4) << 9), 1, m, h, hv);
                });
            }
        }
        __syncthreads();
    }

    // ---- epilogue: FC3+FC4 for t=24; h3(24) is in AH3 slot ws(24)=1 ----
    if (wave >= 5) {
        const int mt = wave - 5;
        bf16x8 a = *(const bf16x8*)(sb + O_AH3 + ((4 + mt) << 9) + (lane << 3));
        f32x4 acc = {0.f, 0.f, 0.f, 0.f};
        acc = MFMA(a, bF3, acc, 0, 0, 0);
#pragma unroll
        for (int r = 0; r < 4; ++r) {
            float u = fmaxf(acc[r] + biasF3, 0.0f);
            float s0 = u * w40, s1 = u * w41;
            s0 += qperm<0xB1>(s0);  s1 += qperm<0xB1>(s1);
            s0 += qperm<0x4E>(s0);  s1 += qperm<0x4E>(s1);
            s0 += qperm<0x124>(s0); s1 += qperm<0x124>(s1);
            s0 += qperm<0x128>(s0); s1 += qperm<0x128>(s1);
            if (ln15 == 0) {
                int mrow = (mt << 4) + ((lane >> 4) << 2) + r;
                float2 o; o.x = s0 + b40; o.y = s1 + b41;
                *(float2*)(out + (size_t)(b0 + mrow) * 50 + 24 * 2) = o;
            }
        }
    }
}

extern "C" void kernel_launch(void* const* d_in, const int* in_sizes, int n_in,
                              void* d_out, int out_size, void* d_ws, size_t ws_size,
                              hipStream_t stream) {
    (void)in_sizes; (void)n_in; (void)d_ws; (void)ws_size; (void)out_size;
    hipFuncSetAttribute((const void*)lstm_fused,
                        hipFuncAttributeMaxDynamicSharedMemorySize, LDS_BYTES);
    lstm_fused<<<dim3(2048), dim3(THREADS), LDS_BYTES, stream>>>(
        (const float*)d_in[0], (const float*)d_in[1],
        (const float*)d_in[2], (const float*)d_in[3],
        (const float*)d_in[4], (const float*)d_in[5],
        (const float*)d_in[6], (const float*)d_in[7],
        (const float*)d_in[8], (const float*)d_in[9],
        (const float*)d_in[10], (const float*)d_in[11],
        (const float*)d_in[12], (const float*)d_in[13],
        (const float*)d_in[14], (const float*)d_in[15],
        (const float*)d_in[16], (const float*)d_in[17],
        (const float*)d_in[18], (const float*)d_in[19],
        (const float*)d_in[20], (const float*)d_in[21],
        (float*)d_out);
}